// Round 17
// baseline (133.362 us; speedup 1.0000x reference)
//
#include <hip/hip_runtime.h>
#include <hip/hip_bf16.h>
#include <math.h>

typedef unsigned int uint32;
typedef unsigned short ushort_t;
typedef __attribute__((ext_vector_type(8))) short s8v;
typedef __attribute__((ext_vector_type(16))) float f16v;
typedef __attribute__((ext_vector_type(2))) unsigned int u2v;

// Problem constants
#define LH 4
#define RH 4
#define DD 64
#define BB 2
#define TT 96
#define NTOK (BB*TT)           // 192
#define HEADS 16
#define VHEADS 10              // heads with r <= l
#define INV_H 0.0625f
#define LOG2E 1.4426950408889634f
#define QKV_BLOCKS 288         // 1152 waves / 4

struct U4 { uint32 x, y, z, w; };

__device__ __forceinline__ uint32 f2bf(float f) {
    return (uint32)__builtin_bit_cast(ushort_t, __float2bfloat16(f));
}
__device__ __forceinline__ uint32 pkbf(float lo, float hi) {
    return f2bf(lo) | (f2bf(hi) << 16);
}
__device__ __forceinline__ float bf2f(uint32 u) {
    return __uint_as_float(u << 16);
}
// hi/lo split of a pair into packed bf16 words (3-product split-GEMM)
__device__ __forceinline__ void hl_pair(float v0, float v1, uint32 &hw, uint32 &lw) {
    uint32 h0 = f2bf(v0), h1 = f2bf(v1);
    hw = h0 | (h1 << 16);
    lw = pkbf(v0 - bf2f(h0), v1 - bf2f(h1));
}
// exchange lanes[0:31] of a with lanes[32:63] of b — verified for A-frags (R10)
__device__ __forceinline__ void hswap(uint32 &a, uint32 &b, int h) {
#if __has_builtin(__builtin_amdgcn_permlane32_swap)
    u2v rr = __builtin_amdgcn_permlane32_swap(a, b, false, false);
    a = rr.x; b = rr.y;
#else
    uint32 xa = (uint32)__shfl_xor((int)a, 32, 64);
    uint32 xb = (uint32)__shfl_xor((int)b, 32, 64);
    uint32 na = (h == 0) ? xb : a;
    uint32 nb = (h == 0) ? b  : xa;
    a = na; b = nb;
#endif
}

// ---------------------------------------------------------------------------
// MFMA q/k/v projections (verbatim R16, PROVEN; zerofill tail removed).
// ---------------------------------------------------------------------------
__global__ __launch_bounds__(256) void pdense_qkv_mfma(
    const float* __restrict__ Xq, const float* __restrict__ Xk, const float* __restrict__ Xv,
    const float* __restrict__ Wq_row, const float* __restrict__ Wq_col, const float* __restrict__ bq,
    const float* __restrict__ Wk_row, const float* __restrict__ Wk_col, const float* __restrict__ bk,
    const float* __restrict__ Wv_row, const float* __restrict__ Wv_col, const float* __restrict__ bv,
    ushort_t* __restrict__ q_bf, ushort_t* __restrict__ k_bf,
    ushort_t* __restrict__ vt_bf)
{
    __shared__ float lds_t1[4][32][68];

    const int wv = threadIdx.x >> 6;
    const int task = blockIdx.x * 4 + wv;            // 0..1151
    const int proj = task / (NTOK * 2);
    const int rem  = task % (NTOK * 2);
    const int token = rem >> 1;
    const int ch = rem & 1;
    const int lane = threadIdx.x & 63;
    const int c5 = lane & 31, h = lane >> 5;
    const int c = ch * 32 + c5;
    const int bI = token / TT, t = token % TT;

    const float* X  = (proj == 0) ? Xq : (proj == 1) ? Xk : Xv;
    const float* Wc = (proj == 0) ? Wq_col : (proj == 1) ? Wk_col : Wv_col;
    const float* Wr = (proj == 0) ? Wq_row : (proj == 1) ? Wk_row : Wv_row;
    const float* bs = (proj == 0) ? bq : (proj == 1) ? bk : bv;
    const float* Xp = X + (size_t)token * 4096;
    const float scale = (proj == 0) ? (INV_H * INV_H * LOG2E) : INV_H;

    const f16v fz = {0,0,0,0,0,0,0,0,0,0,0,0,0,0,0,0};

    f16v t1_0 = fz, t1_1 = fz;
    #pragma unroll
    for (int n = 0; n < 4; ++n) {
        const int k0 = n * 16 + 8 * h;
        U4 ub = { pkbf(Wc[(k0 + 0) * 64 + c], Wc[(k0 + 1) * 64 + c]),
                  pkbf(Wc[(k0 + 2) * 64 + c], Wc[(k0 + 3) * 64 + c]),
                  pkbf(Wc[(k0 + 4) * 64 + c], Wc[(k0 + 5) * 64 + c]),
                  pkbf(Wc[(k0 + 6) * 64 + c], Wc[(k0 + 7) * 64 + c]) };
        s8v bf = __builtin_bit_cast(s8v, ub);
        {
            const float* xr = Xp + (size_t)c5 * 64 + k0;
            float4 xa = *(const float4*)xr, xb = *(const float4*)(xr + 4);
            U4 u = { pkbf(xa.x, xa.y), pkbf(xa.z, xa.w), pkbf(xb.x, xb.y), pkbf(xb.z, xb.w) };
            t1_0 = __builtin_amdgcn_mfma_f32_32x32x16_bf16(__builtin_bit_cast(s8v, u), bf, t1_0, 0, 0, 0);
        }
        {
            const float* xr = Xp + (size_t)(32 + c5) * 64 + k0;
            float4 xa = *(const float4*)xr, xb = *(const float4*)(xr + 4);
            U4 u = { pkbf(xa.x, xa.y), pkbf(xa.z, xa.w), pkbf(xb.x, xb.y), pkbf(xb.z, xb.w) };
            t1_1 = __builtin_amdgcn_mfma_f32_32x32x16_bf16(__builtin_bit_cast(s8v, u), bf, t1_1, 0, 0, 0);
        }
    }

    #pragma unroll
    for (int tt = 0; tt < 16; ++tt) {
        const int i = (tt & 3) + 8 * (tt >> 2) + 4 * h;
        lds_t1[wv][c5][i]      = t1_0[tt];
        lds_t1[wv][c5][32 + i] = t1_1[tt];
    }
    __syncthreads();

    s8v bfr[4];
    #pragma unroll
    for (int n = 0; n < 4; ++n) {
        const float* p = &lds_t1[wv][c5][n * 16 + 8 * h];
        float4 xa = *(const float4*)p, xb = *(const float4*)(p + 4);
        U4 u = { pkbf(xa.x, xa.y), pkbf(xa.z, xa.w), pkbf(xb.x, xb.y), pkbf(xb.z, xb.w) };
        bfr[n] = __builtin_bit_cast(s8v, u);
    }

    #pragma unroll
    for (int At = 0; At < 2; ++At) {
        const int a0 = 32 * At + c5;
        f16v y = fz;
        #pragma unroll
        for (int n = 0; n < 4; ++n) {
            const int k0 = n * 16 + 8 * h;
            U4 ua = { pkbf(Wr[(k0 + 0) * 64 + a0], Wr[(k0 + 1) * 64 + a0]),
                      pkbf(Wr[(k0 + 2) * 64 + a0], Wr[(k0 + 3) * 64 + a0]),
                      pkbf(Wr[(k0 + 4) * 64 + a0], Wr[(k0 + 5) * 64 + a0]),
                      pkbf(Wr[(k0 + 6) * 64 + a0], Wr[(k0 + 7) * 64 + a0]) };
            y = __builtin_amdgcn_mfma_f32_32x32x16_bf16(
                    __builtin_bit_cast(s8v, ua), bfr[n], y, 0, 0, 0);
        }
        #pragma unroll
        for (int rg = 0; rg < 4; ++rg) {
            #pragma unroll
            for (int e = 0; e < 4; ++e) {
                const int a = 32 * At + 8 * rg + 4 * h + e;
                const float val = (y[rg * 4 + e] + bs[a * 64 + c]) * scale;
                const ushort_t ov = (ushort_t)f2bf(val);
                const size_t base =
                    ((size_t)((bI * HEADS + (a >> 4) * RH + (c >> 4)) * TT + t)) * 256;
                if (proj == 0)      q_bf[base + (a & 15) * 16 + (c & 15)] = ov;
                else if (proj == 1) k_bf[base + (a & 15) * 16 + (c & 15)] = ov;
                else                vt_bf[base + (c & 15) * 16 + (a & 15)] = ov;
            }
        }
    }
}

// ---------------------------------------------------------------------------
// Fused attention + out-projection. Block = (batch, token-pair).
// Wave wv handles vheads {wv, wv+4, wv+8}: full-j (no split -> Z lane-local),
// same verified QK/softmax/PV math (48 j-pair iters), PV epilogue -> LDS att
// slab (stride-68, zero-init covers r>l mask). Then 4 waves run the R16-proven
// out-projection body with A-frags read from LDS.
// ---------------------------------------------------------------------------
__global__ __launch_bounds__(256) void attn_out_fused(
    const ushort_t* __restrict__ q_bf,
    const ushort_t* __restrict__ k_bf,
    const ushort_t* __restrict__ vt_bf,
    const float* __restrict__ Wo_row, const float* __restrict__ Wo_col,
    const float* __restrict__ bo, float* __restrict__ out)
{
    __shared__ float attS[2 * 64 * 68];     // [tok][row][col], stride 68
    __shared__ float lds_t1[4][32][68];

    const int ip = blockIdx.x % (TT / 2);
    const int bI = blockIdx.x / (TT / 2);
    const int i0 = ip * 2;
    const int tid = threadIdx.x;
    const int wv = tid >> 6;
    const int lane = tid & 63;
    const int c5 = lane & 31;
    const int h  = lane >> 5;
    const f16v fz = {0,0,0,0,0,0,0,0,0,0,0,0,0,0,0,0};

    // zero att slab (covers the r>l masked head tiles)
    for (int z = tid; z < 2 * 64 * 68; z += 256) attS[z] = 0.f;
    __syncthreads();

    // ---- attention: each wave owns whole vheads ----
    const int frow = (c5 & 15) * 16 + 8 * h;
    for (int vh = wv; vh < VHEADS; vh += 4) {
        const int l = (vh >= 1) + (vh >= 3) + (vh >= 6);
        const int r = vh - (l * (l + 1)) / 2;
        const int head = l * RH + r;
        const size_t hb = (size_t)(bI * HEADS + head) * TT * 256;

        s8v qf = *(const s8v*)(q_bf + hb + (size_t)(i0 + (c5 >> 4)) * 256 + frow);
        const ushort_t* kb = k_bf + hb + frow;
        const ushort_t* vb = vt_bf + hb + frow;

        // pass 1: denominators (lane-local; full j range)
        float ls[8] = {0,0,0,0,0,0,0,0};
        #pragma unroll 4
        for (int jp = 0; jp < TT / 2; ++jp) {
            const int j0g = jp * 2;
            s8v kf = *(const s8v*)(kb + (size_t)(j0g + (c5 >> 4)) * 256);
            f16v d = __builtin_amdgcn_mfma_f32_32x32x16_bf16(kf, qf, fz, 0, 0, 0);
            #pragma unroll
            for (int t = 0; t < 8; ++t)
                ls[t] += exp2f(d[t]) + exp2f(d[t + 8]);
        }
        float inv[8];
        #pragma unroll
        for (int t = 0; t < 8; ++t) inv[t] = 1.f / ls[t];

        // pass 2: recompute, normalize, hswap A-frag redistribute, PV
        f16v pv = fz;
        #pragma unroll 2
        for (int jp = 0; jp < TT / 2; ++jp) {
            const int j0g = jp * 2;
            s8v kf = *(const s8v*)(kb + (size_t)(j0g + (c5 >> 4)) * 256);
            f16v d = __builtin_amdgcn_mfma_f32_32x32x16_bf16(kf, qf, fz, 0, 0, 0);
            float w[16];
            #pragma unroll
            for (int t = 0; t < 8; ++t) {
                w[t]     = exp2f(d[t])     * inv[t];
                w[t + 8] = exp2f(d[t + 8]) * inv[t];
            }
            uint32 A0 = pkbf(w[0],  w[1]),  A1 = pkbf(w[2],  w[3]);
            uint32 A2 = pkbf(w[4],  w[5]),  A3 = pkbf(w[6],  w[7]);
            uint32 B0 = pkbf(w[8],  w[9]),  B1 = pkbf(w[10], w[11]);
            uint32 B2 = pkbf(w[12], w[13]), B3 = pkbf(w[14], w[15]);
            hswap(A2, A0, h); hswap(A3, A1, h);
            hswap(B2, B0, h); hswap(B3, B1, h);
            U4 fa = {A0, A1, A2, A3};
            U4 fb = {B0, B1, B2, B3};
            s8v vf0 = *(const s8v*)(vb + (size_t)(j0g + 0) * 256);
            s8v vf1 = *(const s8v*)(vb + (size_t)(j0g + 1) * 256);
            pv = __builtin_amdgcn_mfma_f32_32x32x16_bf16(__builtin_bit_cast(s8v, fa), vf0, pv, 0, 0, 0);
            pv = __builtin_amdgcn_mfma_f32_32x32x16_bf16(__builtin_bit_cast(s8v, fb), vf1, pv, 0, 0, 0);
        }

        // epilogue: write this head's tile into the LDS att slab
        if (c5 < 16) {
            #pragma unroll
            for (int reg = 0; reg < 16; ++reg) {
                const int row = (reg & 3) + 8 * (reg >> 2) + 4 * h;
                const int i = row >> 4, p = row & 15;
                attS[((i * 64) + l * 16 + p) * 68 + r * 16 + c5] = pv[reg];
            }
        }
    }
    __syncthreads();

    // ---- out-projection (R16-proven hi/lo body; A from LDS att slab) ----
    const int tok = wv >> 1, ch = wv & 1;
    const int c = ch * 32 + c5;

    f16v t1_0 = fz, t1_1 = fz;
    #pragma unroll
    for (int n = 0; n < 4; ++n) {
        const int k0 = n * 16 + 8 * h;
        uint32 bh0, bl0, bh1, bl1, bh2, bl2, bh3, bl3;
        hl_pair(Wo_col[(k0 + 0) * 64 + c], Wo_col[(k0 + 1) * 64 + c], bh0, bl0);
        hl_pair(Wo_col[(k0 + 2) * 64 + c], Wo_col[(k0 + 3) * 64 + c], bh1, bl1);
        hl_pair(Wo_col[(k0 + 4) * 64 + c], Wo_col[(k0 + 5) * 64 + c], bh2, bl2);
        hl_pair(Wo_col[(k0 + 6) * 64 + c], Wo_col[(k0 + 7) * 64 + c], bh3, bl3);
        U4 ubh = {bh0, bh1, bh2, bh3}, ubl = {bl0, bl1, bl2, bl3};
        s8v bh = __builtin_bit_cast(s8v, ubh), bl = __builtin_bit_cast(s8v, ubl);
        #pragma unroll
        for (int T = 0; T < 2; ++T) {
            const float* xr = &attS[((tok * 64) + 32 * T + c5) * 68 + k0];
            float4 xa = *(const float4*)xr, xb = *(const float4*)(xr + 4);
            uint32 hw0, lw0, hw1, lw1, hw2, lw2, hw3, lw3;
            hl_pair(xa.x, xa.y, hw0, lw0);
            hl_pair(xa.z, xa.w, hw1, lw1);
            hl_pair(xb.x, xb.y, hw2, lw2);
            hl_pair(xb.z, xb.w, hw3, lw3);
            U4 uh = {hw0, hw1, hw2, hw3}, ul = {lw0, lw1, lw2, lw3};
            s8v ah = __builtin_bit_cast(s8v, uh), al = __builtin_bit_cast(s8v, ul);
            f16v acc = (T == 0) ? t1_0 : t1_1;
            acc = __builtin_amdgcn_mfma_f32_32x32x16_bf16(ah, bh, acc, 0, 0, 0);
            acc = __builtin_amdgcn_mfma_f32_32x32x16_bf16(al, bh, acc, 0, 0, 0);
            acc = __builtin_amdgcn_mfma_f32_32x32x16_bf16(ah, bl, acc, 0, 0, 0);
            if (T == 0) t1_0 = acc; else t1_1 = acc;
        }
    }

    #pragma unroll
    for (int tt = 0; tt < 16; ++tt) {
        const int i = (tt & 3) + 8 * (tt >> 2) + 4 * h;
        lds_t1[wv][c5][i]      = t1_0[tt];
        lds_t1[wv][c5][32 + i] = t1_1[tt];
    }
    __syncthreads();

    s8v bfh[4], bfl[4];
    #pragma unroll
    for (int n = 0; n < 4; ++n) {
        const float* p = &lds_t1[wv][c5][n * 16 + 8 * h];
        float4 xa = *(const float4*)p, xb = *(const float4*)(p + 4);
        uint32 h0, l0, h1, l1, h2, l2, h3, l3;
        hl_pair(xa.x, xa.y, h0, l0);
        hl_pair(xa.z, xa.w, h1, l1);
        hl_pair(xb.x, xb.y, h2, l2);
        hl_pair(xb.z, xb.w, h3, l3);
        U4 uh = {h0, h1, h2, h3}, ul = {l0, l1, l2, l3};
        bfh[n] = __builtin_bit_cast(s8v, uh);
        bfl[n] = __builtin_bit_cast(s8v, ul);
    }

    #pragma unroll
    for (int At = 0; At < 2; ++At) {
        const int a0 = 32 * At + c5;
        f16v y = fz;
        #pragma unroll
        for (int n = 0; n < 4; ++n) {
            const int k0 = n * 16 + 8 * h;
            uint32 ah0, al0, ah1, al1, ah2, al2, ah3, al3;
            hl_pair(Wo_row[(k0 + 0) * 64 + a0], Wo_row[(k0 + 1) * 64 + a0], ah0, al0);
            hl_pair(Wo_row[(k0 + 2) * 64 + a0], Wo_row[(k0 + 3) * 64 + a0], ah1, al1);
            hl_pair(Wo_row[(k0 + 4) * 64 + a0], Wo_row[(k0 + 5) * 64 + a0], ah2, al2);
            hl_pair(Wo_row[(k0 + 6) * 64 + a0], Wo_row[(k0 + 7) * 64 + a0], ah3, al3);
            U4 uah = {ah0, ah1, ah2, ah3}, ual = {al0, al1, al2, al3};
            s8v awh = __builtin_bit_cast(s8v, uah), awl = __builtin_bit_cast(s8v, ual);
            y = __builtin_amdgcn_mfma_f32_32x32x16_bf16(awh, bfh[n], y, 0, 0, 0);
            y = __builtin_amdgcn_mfma_f32_32x32x16_bf16(awh, bfl[n], y, 0, 0, 0);
            y = __builtin_amdgcn_mfma_f32_32x32x16_bf16(awl, bfh[n], y, 0, 0, 0);
        }
        #pragma unroll
        for (int rg = 0; rg < 4; ++rg) {
            #pragma unroll
            for (int e = 0; e < 4; ++e) {
                const int a = 32 * At + 8 * rg + 4 * h + e;
                out[(size_t)(bI * TT + i0 + tok) * 4096 + a * 64 + c] =
                    (y[rg * 4 + e] + bo[a * 64 + c]) * INV_H;
            }
        }
    }
}

// ---------------------------------------------------------------------------
extern "C" void kernel_launch(void* const* d_in, const int* in_sizes, int n_in,
                              void* d_out, int out_size, void* d_ws, size_t ws_size,
                              hipStream_t stream) {
    const float* queries = (const float*)d_in[0];
    const float* keys    = (const float*)d_in[1];
    const float* values  = (const float*)d_in[2];
    const float* Wq_row  = (const float*)d_in[3];
    const float* Wq_col  = (const float*)d_in[4];
    const float* bq      = (const float*)d_in[5];
    const float* Wk_row  = (const float*)d_in[6];
    const float* Wk_col  = (const float*)d_in[7];
    const float* bk      = (const float*)d_in[8];
    const float* Wv_row  = (const float*)d_in[9];
    const float* Wv_col  = (const float*)d_in[10];
    const float* bv      = (const float*)d_in[11];
    const float* Wo_row  = (const float*)d_in[12];
    const float* Wo_col  = (const float*)d_in[13];
    const float* bo      = (const float*)d_in[14];
    float* out = (float*)d_out;

    const size_t SEP = (size_t)BB * HEADS * TT * 256;   // 786432 elements
    ushort_t* q_bf  = (ushort_t*)d_ws;
    ushort_t* k_bf  = q_bf + SEP;
    ushort_t* vt_bf = k_bf + SEP;

    pdense_qkv_mfma<<<QKV_BLOCKS, 256, 0, stream>>>(
        queries, keys, values,
        Wq_row, Wq_col, bq, Wk_row, Wk_col, bk, Wv_row, Wv_col, bv,
        q_bf, k_bf, vt_bf);

    attn_out_fused<<<BB * (TT / 2), 256, 0, stream>>>(
        q_bf, k_bf, vt_bf, Wo_row, Wo_col, bo, out);
}

// Round 18
// 61.271 us; speedup vs baseline: 2.1766x; 2.1766x over previous
//
#include <hip/hip_runtime.h>
#include <hip/hip_bf16.h>
#include <math.h>

typedef unsigned int uint32;
typedef unsigned short ushort_t;
typedef __attribute__((ext_vector_type(8))) short s8v;
typedef __attribute__((ext_vector_type(16))) float f16v;
typedef __attribute__((ext_vector_type(2))) unsigned int u2v;

// Problem constants
#define LH 4
#define RH 4
#define DD 64
#define BB 2
#define TT 96
#define NTOK (BB*TT)           // 192
#define HEADS 16
#define VHEADS 10              // heads with r <= l
#define INV_H 0.0625f
#define LOG2E 1.4426950408889634f

struct U4 { uint32 x, y, z, w; };

__device__ __forceinline__ uint32 f2bf(float f) {
    return (uint32)__builtin_bit_cast(ushort_t, __float2bfloat16(f));
}
__device__ __forceinline__ uint32 pkbf(float lo, float hi) {
    return f2bf(lo) | (f2bf(hi) << 16);
}
__device__ __forceinline__ float bf2f(uint32 u) {
    return __uint_as_float(u << 16);
}
// hi/lo split of a pair into packed bf16 words (3-product split-GEMM)
__device__ __forceinline__ void hl_pair(float v0, float v1, uint32 &hw, uint32 &lw) {
    uint32 h0 = f2bf(v0), h1 = f2bf(v1);
    hw = h0 | (h1 << 16);
    lw = pkbf(v0 - bf2f(h0), v1 - bf2f(h1));
}
// exchange lanes[0:31] of a with lanes[32:63] of b — verified for A-frags (R10)
__device__ __forceinline__ void hswap(uint32 &a, uint32 &b, int h) {
#if __has_builtin(__builtin_amdgcn_permlane32_swap)
    u2v rr = __builtin_amdgcn_permlane32_swap(a, b, false, false);
    a = rr.x; b = rr.y;
#else
    uint32 xa = (uint32)__shfl_xor((int)a, 32, 64);
    uint32 xb = (uint32)__shfl_xor((int)b, 32, 64);
    uint32 na = (h == 0) ? xb : a;
    uint32 nb = (h == 0) ? b  : xa;
    a = na; b = nb;
#endif
}

// ---------------------------------------------------------------------------
// MFMA q/k/v projections (R16-proven math), ONE WAVE PER BLOCK (64 thr,
// 1152 blocks) — no inter-wave barrier coupling, 4.5 blocks/CU.
// ---------------------------------------------------------------------------
__global__ __launch_bounds__(64) void pdense_qkv_mfma(
    const float* __restrict__ Xq, const float* __restrict__ Xk, const float* __restrict__ Xv,
    const float* __restrict__ Wq_row, const float* __restrict__ Wq_col, const float* __restrict__ bq,
    const float* __restrict__ Wk_row, const float* __restrict__ Wk_col, const float* __restrict__ bk,
    const float* __restrict__ Wv_row, const float* __restrict__ Wv_col, const float* __restrict__ bv,
    ushort_t* __restrict__ q_bf, ushort_t* __restrict__ k_bf,
    ushort_t* __restrict__ vt_bf)
{
    __shared__ float lds_t1[32][68];

    const int task = blockIdx.x;                     // 0..1151
    const int proj = task / (NTOK * 2);
    const int rem  = task % (NTOK * 2);
    const int token = rem >> 1;
    const int ch = rem & 1;
    const int lane = threadIdx.x;
    const int c5 = lane & 31, h = lane >> 5;
    const int c = ch * 32 + c5;
    const int bI = token / TT, t = token % TT;

    const float* X  = (proj == 0) ? Xq : (proj == 1) ? Xk : Xv;
    const float* Wc = (proj == 0) ? Wq_col : (proj == 1) ? Wk_col : Wv_col;
    const float* Wr = (proj == 0) ? Wq_row : (proj == 1) ? Wk_row : Wv_row;
    const float* bs = (proj == 0) ? bq : (proj == 1) ? bk : bv;
    const float* Xp = X + (size_t)token * 4096;
    const float scale = (proj == 0) ? (INV_H * INV_H * LOG2E) : INV_H;

    const f16v fz = {0,0,0,0,0,0,0,0,0,0,0,0,0,0,0,0};

    // GEMM1: T1 = X @ Wc
    f16v t1_0 = fz, t1_1 = fz;
    #pragma unroll
    for (int n = 0; n < 4; ++n) {
        const int k0 = n * 16 + 8 * h;
        U4 ub = { pkbf(Wc[(k0 + 0) * 64 + c], Wc[(k0 + 1) * 64 + c]),
                  pkbf(Wc[(k0 + 2) * 64 + c], Wc[(k0 + 3) * 64 + c]),
                  pkbf(Wc[(k0 + 4) * 64 + c], Wc[(k0 + 5) * 64 + c]),
                  pkbf(Wc[(k0 + 6) * 64 + c], Wc[(k0 + 7) * 64 + c]) };
        s8v bf = __builtin_bit_cast(s8v, ub);
        {
            const float* xr = Xp + (size_t)c5 * 64 + k0;
            float4 xa = *(const float4*)xr, xb = *(const float4*)(xr + 4);
            U4 u = { pkbf(xa.x, xa.y), pkbf(xa.z, xa.w), pkbf(xb.x, xb.y), pkbf(xb.z, xb.w) };
            t1_0 = __builtin_amdgcn_mfma_f32_32x32x16_bf16(__builtin_bit_cast(s8v, u), bf, t1_0, 0, 0, 0);
        }
        {
            const float* xr = Xp + (size_t)(32 + c5) * 64 + k0;
            float4 xa = *(const float4*)xr, xb = *(const float4*)(xr + 4);
            U4 u = { pkbf(xa.x, xa.y), pkbf(xa.z, xa.w), pkbf(xb.x, xb.y), pkbf(xb.z, xb.w) };
            t1_1 = __builtin_amdgcn_mfma_f32_32x32x16_bf16(__builtin_bit_cast(s8v, u), bf, t1_1, 0, 0, 0);
        }
    }

    // LDS transpose roundtrip (PROVEN B-frag rebuild)
    #pragma unroll
    for (int tt = 0; tt < 16; ++tt) {
        const int i = (tt & 3) + 8 * (tt >> 2) + 4 * h;
        lds_t1[c5][i]      = t1_0[tt];
        lds_t1[c5][32 + i] = t1_1[tt];
    }
    __syncthreads();

    s8v bfr[4];
    #pragma unroll
    for (int n = 0; n < 4; ++n) {
        const float* p = &lds_t1[c5][n * 16 + 8 * h];
        float4 xa = *(const float4*)p, xb = *(const float4*)(p + 4);
        U4 u = { pkbf(xa.x, xa.y), pkbf(xa.z, xa.w), pkbf(xb.x, xb.y), pkbf(xb.z, xb.w) };
        bfr[n] = __builtin_bit_cast(s8v, u);
    }

    // GEMM2 + epilogue
    #pragma unroll
    for (int At = 0; At < 2; ++At) {
        const int a0 = 32 * At + c5;
        f16v y = fz;
        #pragma unroll
        for (int n = 0; n < 4; ++n) {
            const int k0 = n * 16 + 8 * h;
            U4 ua = { pkbf(Wr[(k0 + 0) * 64 + a0], Wr[(k0 + 1) * 64 + a0]),
                      pkbf(Wr[(k0 + 2) * 64 + a0], Wr[(k0 + 3) * 64 + a0]),
                      pkbf(Wr[(k0 + 4) * 64 + a0], Wr[(k0 + 5) * 64 + a0]),
                      pkbf(Wr[(k0 + 6) * 64 + a0], Wr[(k0 + 7) * 64 + a0]) };
            y = __builtin_amdgcn_mfma_f32_32x32x16_bf16(
                    __builtin_bit_cast(s8v, ua), bfr[n], y, 0, 0, 0);
        }
        #pragma unroll
        for (int rg = 0; rg < 4; ++rg) {
            #pragma unroll
            for (int e = 0; e < 4; ++e) {
                const int a = 32 * At + 8 * rg + 4 * h + e;
                const float val = (y[rg * 4 + e] + bs[a * 64 + c]) * scale;
                const ushort_t ov = (ushort_t)f2bf(val);
                const size_t base =
                    ((size_t)((bI * HEADS + (a >> 4) * RH + (c >> 4)) * TT + t)) * 256;
                if (proj == 0)      q_bf[base + (a & 15) * 16 + (c & 15)] = ov;
                else if (proj == 1) k_bf[base + (a & 15) * 16 + (c & 15)] = ov;
                else                vt_bf[base + (c & 15) * 16 + (a & 15)] = ov;
            }
        }
    }
}

// ---------------------------------------------------------------------------
// MFMA out-projection (R16-proven hi/lo), ONE WAVE PER BLOCK (384 blocks).
// ---------------------------------------------------------------------------
__global__ __launch_bounds__(64) void pdense_out_mfma2(
    const float* __restrict__ att,
    const float* __restrict__ Wo_row, const float* __restrict__ Wo_col,
    const float* __restrict__ bo, float* __restrict__ out)
{
    __shared__ float lds_t1[32][68];

    const int task = blockIdx.x;                     // 0..383
    const int token = task >> 1, ch = task & 1;
    const int lane = threadIdx.x;
    const int c5 = lane & 31, h = lane >> 5;
    const int c = ch * 32 + c5;

    const float* Xp = att + (size_t)token * 4096;
    const f16v fz = {0,0,0,0,0,0,0,0,0,0,0,0,0,0,0,0};

    f16v t1_0 = fz, t1_1 = fz;
    #pragma unroll
    for (int n = 0; n < 4; ++n) {
        const int k0 = n * 16 + 8 * h;
        uint32 bh0, bl0, bh1, bl1, bh2, bl2, bh3, bl3;
        hl_pair(Wo_col[(k0 + 0) * 64 + c], Wo_col[(k0 + 1) * 64 + c], bh0, bl0);
        hl_pair(Wo_col[(k0 + 2) * 64 + c], Wo_col[(k0 + 3) * 64 + c], bh1, bl1);
        hl_pair(Wo_col[(k0 + 4) * 64 + c], Wo_col[(k0 + 5) * 64 + c], bh2, bl2);
        hl_pair(Wo_col[(k0 + 6) * 64 + c], Wo_col[(k0 + 7) * 64 + c], bh3, bl3);
        U4 ubh = {bh0, bh1, bh2, bh3}, ubl = {bl0, bl1, bl2, bl3};
        s8v bh = __builtin_bit_cast(s8v, ubh), bl = __builtin_bit_cast(s8v, ubl);
        #pragma unroll
        for (int T = 0; T < 2; ++T) {
            const float* xr = Xp + (size_t)(32 * T + c5) * 64 + k0;
            float4 xa = *(const float4*)xr, xb = *(const float4*)(xr + 4);
            uint32 hw0, lw0, hw1, lw1, hw2, lw2, hw3, lw3;
            hl_pair(xa.x, xa.y, hw0, lw0);
            hl_pair(xa.z, xa.w, hw1, lw1);
            hl_pair(xb.x, xb.y, hw2, lw2);
            hl_pair(xb.z, xb.w, hw3, lw3);
            U4 uh = {hw0, hw1, hw2, hw3}, ul = {lw0, lw1, lw2, lw3};
            s8v ah = __builtin_bit_cast(s8v, uh), al = __builtin_bit_cast(s8v, ul);
            f16v acc = (T == 0) ? t1_0 : t1_1;
            acc = __builtin_amdgcn_mfma_f32_32x32x16_bf16(ah, bh, acc, 0, 0, 0);
            acc = __builtin_amdgcn_mfma_f32_32x32x16_bf16(al, bh, acc, 0, 0, 0);
            acc = __builtin_amdgcn_mfma_f32_32x32x16_bf16(ah, bl, acc, 0, 0, 0);
            if (T == 0) t1_0 = acc; else t1_1 = acc;
        }
    }

    #pragma unroll
    for (int tt = 0; tt < 16; ++tt) {
        const int i = (tt & 3) + 8 * (tt >> 2) + 4 * h;
        lds_t1[c5][i]      = t1_0[tt];
        lds_t1[c5][32 + i] = t1_1[tt];
    }
    __syncthreads();

    s8v bfh[4], bfl[4];
    #pragma unroll
    for (int n = 0; n < 4; ++n) {
        const float* p = &lds_t1[c5][n * 16 + 8 * h];
        float4 xa = *(const float4*)p, xb = *(const float4*)(p + 4);
        uint32 h0, l0, h1, l1, h2, l2, h3, l3;
        hl_pair(xa.x, xa.y, h0, l0);
        hl_pair(xa.z, xa.w, h1, l1);
        hl_pair(xb.x, xb.y, h2, l2);
        hl_pair(xb.z, xb.w, h3, l3);
        U4 uh = {h0, h1, h2, h3}, ul = {l0, l1, l2, l3};
        bfh[n] = __builtin_bit_cast(s8v, uh);
        bfl[n] = __builtin_bit_cast(s8v, ul);
    }

    #pragma unroll
    for (int At = 0; At < 2; ++At) {
        const int a0 = 32 * At + c5;
        f16v y = fz;
        #pragma unroll
        for (int n = 0; n < 4; ++n) {
            const int k0 = n * 16 + 8 * h;
            uint32 ah0, al0, ah1, al1, ah2, al2, ah3, al3;
            hl_pair(Wo_row[(k0 + 0) * 64 + a0], Wo_row[(k0 + 1) * 64 + a0], ah0, al0);
            hl_pair(Wo_row[(k0 + 2) * 64 + a0], Wo_row[(k0 + 3) * 64 + a0], ah1, al1);
            hl_pair(Wo_row[(k0 + 4) * 64 + a0], Wo_row[(k0 + 5) * 64 + a0], ah2, al2);
            hl_pair(Wo_row[(k0 + 6) * 64 + a0], Wo_row[(k0 + 7) * 64 + a0], ah3, al3);
            U4 uah = {ah0, ah1, ah2, ah3}, ual = {al0, al1, al2, al3};
            s8v awh = __builtin_bit_cast(s8v, uah), awl = __builtin_bit_cast(s8v, ual);
            y = __builtin_amdgcn_mfma_f32_32x32x16_bf16(awh, bfh[n], y, 0, 0, 0);
            y = __builtin_amdgcn_mfma_f32_32x32x16_bf16(awh, bfl[n], y, 0, 0, 0);
            y = __builtin_amdgcn_mfma_f32_32x32x16_bf16(awl, bfh[n], y, 0, 0, 0);
        }
        #pragma unroll
        for (int rg = 0; rg < 4; ++rg) {
            #pragma unroll
            for (int e = 0; e < 4; ++e) {
                const int a = 32 * At + 8 * rg + 4 * h + e;
                out[(size_t)token * 4096 + a * 64 + c] =
                    (y[rg * 4 + e] + bo[a * 64 + c]) * INV_H;
            }
        }
    }
}

// ---------------------------------------------------------------------------
// Zerofill for att buffer (r>l masked tiles) — tiny standalone kernel.
// ---------------------------------------------------------------------------
__global__ __launch_bounds__(256) void zerofill_att(float4* __restrict__ att4)
{
    #pragma unroll
    for (int k2 = 0; k2 < 16; ++k2)
        att4[(size_t)blockIdx.x * 4096 + k2 * 256 + threadIdx.x] =
            float4{0.f, 0.f, 0.f, 0.f};
}

// ---------------------------------------------------------------------------
// MFMA attention v2 (verbatim R10/R13/R16, verified). 960 blocks x 4 waves.
// ---------------------------------------------------------------------------
__global__ __launch_bounds__(256, 4) void attn_kernel(
    const ushort_t* __restrict__ q_bf,
    const ushort_t* __restrict__ k_bf,
    const ushort_t* __restrict__ vt_bf,
    float* __restrict__ att)
{
    __shared__ float lds_z[4][64][9];
    __shared__ float lds_pv[4][64][17];

    const int ip = blockIdx.x % (TT / 2);
    const int vh = (blockIdx.x / (TT / 2)) % VHEADS;
    const int bI = blockIdx.x / ((TT / 2) * VHEADS);
    const int l = (vh >= 1) + (vh >= 3) + (vh >= 6);
    const int r = vh - (l * (l + 1)) / 2;
    const int head = l * RH + r;
    const int i0 = ip * 2;
    const int lane = threadIdx.x & 63;
    const int wv = threadIdx.x >> 6;
    const int c5 = lane & 31;
    const int h  = lane >> 5;

    const size_t hb = (size_t)(bI * HEADS + head) * TT * 256;
    const int frow = (c5 & 15) * 16 + 8 * h;

    s8v qf = *(const s8v*)(q_bf + hb + (size_t)(i0 + (c5 >> 4)) * 256 + frow);
    const ushort_t* kb = k_bf + hb + frow;
    const ushort_t* vb = vt_bf + hb + frow;

    const int jb = wv * (TT / 4);
    const f16v fz16 = {0,0,0,0,0,0,0,0,0,0,0,0,0,0,0,0};

    float ls[8] = {0,0,0,0,0,0,0,0};
    #pragma unroll 3
    for (int jp = 0; jp < 12; ++jp) {
        const int j0g = jb + jp * 2;
        s8v kf = *(const s8v*)(kb + (size_t)(j0g + (c5 >> 4)) * 256);
        f16v d = __builtin_amdgcn_mfma_f32_32x32x16_bf16(kf, qf, fz16, 0, 0, 0);
        #pragma unroll
        for (int t = 0; t < 8; ++t)
            ls[t] += exp2f(d[t]) + exp2f(d[t + 8]);
    }
    #pragma unroll
    for (int t = 0; t < 8; ++t) lds_z[wv][lane][t] = ls[t];
    __syncthreads();
    float inv[8];
    #pragma unroll
    for (int t = 0; t < 8; ++t) {
        float s = lds_z[0][lane][t] + lds_z[1][lane][t]
                + lds_z[2][lane][t] + lds_z[3][lane][t];
        inv[t] = 1.f / s;
    }

    f16v pv = fz16;
    #pragma unroll 2
    for (int jp = 0; jp < 12; ++jp) {
        const int j0g = jb + jp * 2;
        s8v kf = *(const s8v*)(kb + (size_t)(j0g + (c5 >> 4)) * 256);
        f16v d = __builtin_amdgcn_mfma_f32_32x32x16_bf16(kf, qf, fz16, 0, 0, 0);
        float w[16];
        #pragma unroll
        for (int t = 0; t < 8; ++t) {
            w[t]     = exp2f(d[t])     * inv[t];
            w[t + 8] = exp2f(d[t + 8]) * inv[t];
        }
        uint32 A0 = pkbf(w[0],  w[1]),  A1 = pkbf(w[2],  w[3]);
        uint32 A2 = pkbf(w[4],  w[5]),  A3 = pkbf(w[6],  w[7]);
        uint32 B0 = pkbf(w[8],  w[9]),  B1 = pkbf(w[10], w[11]);
        uint32 B2 = pkbf(w[12], w[13]), B3 = pkbf(w[14], w[15]);
        hswap(A2, A0, h); hswap(A3, A1, h);
        hswap(B2, B0, h); hswap(B3, B1, h);
        U4 fa = {A0, A1, A2, A3};
        U4 fb = {B0, B1, B2, B3};
        s8v vf0 = *(const s8v*)(vb + (size_t)(j0g + 0) * 256);
        s8v vf1 = *(const s8v*)(vb + (size_t)(j0g + 1) * 256);
        pv = __builtin_amdgcn_mfma_f32_32x32x16_bf16(__builtin_bit_cast(s8v, fa), vf0, pv, 0, 0, 0);
        pv = __builtin_amdgcn_mfma_f32_32x32x16_bf16(__builtin_bit_cast(s8v, fb), vf1, pv, 0, 0, 0);
    }

    #pragma unroll
    for (int t = 0; t < 16; ++t) lds_pv[wv][lane][t] = pv[t];
    __syncthreads();

    if (c5 < 16) {
        #pragma unroll
        for (int rr = 0; rr < 4; ++rr) {
            const int reg = wv * 4 + rr;
            float v = lds_pv[0][lane][reg] + lds_pv[1][lane][reg]
                    + lds_pv[2][lane][reg] + lds_pv[3][lane][reg];
            const int row = rr + 8 * wv + 4 * h;
            const int i = row >> 4, p = row & 15;
            att[((size_t)(bI * TT + i0 + i) * DD + l * 16 + p) * DD + r * 16 + c5] = v;
        }
    }
}

// ---------------------------------------------------------------------------
extern "C" void kernel_launch(void* const* d_in, const int* in_sizes, int n_in,
                              void* d_out, int out_size, void* d_ws, size_t ws_size,
                              hipStream_t stream) {
    const float* queries = (const float*)d_in[0];
    const float* keys    = (const float*)d_in[1];
    const float* values  = (const float*)d_in[2];
    const float* Wq_row  = (const float*)d_in[3];
    const float* Wq_col  = (const float*)d_in[4];
    const float* bq      = (const float*)d_in[5];
    const float* Wk_row  = (const float*)d_in[6];
    const float* Wk_col  = (const float*)d_in[7];
    const float* bk      = (const float*)d_in[8];
    const float* Wv_row  = (const float*)d_in[9];
    const float* Wv_col  = (const float*)d_in[10];
    const float* bv      = (const float*)d_in[11];
    const float* Wo_row  = (const float*)d_in[12];
    const float* Wo_col  = (const float*)d_in[13];
    const float* bo      = (const float*)d_in[14];
    float* out = (float*)d_out;

    const size_t SEP = (size_t)BB * HEADS * TT * 256;   // 786432 elements
    ushort_t* q_bf  = (ushort_t*)d_ws;
    ushort_t* k_bf  = q_bf + SEP;
    ushort_t* vt_bf = k_bf + SEP;
    float*    att   = (float*)(vt_bf + SEP);

    // zerofill att (covers r>l masked tiles); runs concurrent with qkv
    zerofill_att<<<48, 256, 0, stream>>>((float4*)att);

    pdense_qkv_mfma<<<3 * NTOK * 2, 64, 0, stream>>>(
        queries, keys, values,
        Wq_row, Wq_col, bq, Wk_row, Wk_col, bk, Wv_row, Wv_col, bv,
        q_bf, k_bf, vt_bf);

    attn_kernel<<<BB * VHEADS * (TT / 2), 256, 0, stream>>>(q_bf, k_bf, vt_bf, att);

    pdense_out_mfma2<<<NTOK * 2, 64, 0, stream>>>(
        att, Wo_row, Wo_col, bo, out);
}